// Round 6
// baseline (356.806 us; speedup 1.0000x reference)
//
#include <hip/hip_runtime.h>
#include <math.h>

#define HIDN 2048
#define NHEADS 16
#define HDIM 128
#define SEQ 2048
#define NB 2

// scale * log2(e), folded into Wq/bq so S arrives pre-scaled for exp2.
#define C2 0.12751744154f

typedef __bf16 bf16x8 __attribute__((ext_vector_type(8)));
typedef float f32x4 __attribute__((ext_vector_type(4)));

__device__ __forceinline__ unsigned short f32_to_bf16(float f) {
  unsigned int u = __float_as_uint(f);
  u += 0x7FFFu + ((u >> 16) & 1u);   // round-to-nearest-even
  return (unsigned short)(u >> 16);
}

__device__ __forceinline__ unsigned pack_bf16x2(float a, float b) {
  return (unsigned)f32_to_bf16(a) | ((unsigned)f32_to_bf16(b) << 16);
}

// pack two f32 to bf16x2 by TRUNCATION in one v_perm_b32.
__device__ __forceinline__ unsigned pack_bf16x2_trunc(float a, float b) {
  return __builtin_amdgcn_perm(__float_as_uint(b), __float_as_uint(a), 0x07060302u);
}

// async global->LDS, 16B/lane. LDS dest is wave-uniform base + lane*16 (m104/m108).
__device__ __forceinline__ void gload_lds16(const void* g, void* l) {
  __builtin_amdgcn_global_load_lds(
      (__attribute__((address_space(1))) void*)(g),
      (__attribute__((address_space(3))) void*)(l), 16, 0, 0);
}

// ---------------- elementwise cast fp32 -> bf16 ----------------
__global__ __launch_bounds__(256) void cast_f32_bf16(
    const float* __restrict__ in, unsigned short* __restrict__ out, int n4) {
  int i = blockIdx.x * blockDim.x + threadIdx.x;
  if (i >= n4) return;
  float4 v = ((const float4*)in)[i];
  ushort4 o;
  o.x = f32_to_bf16(v.x); o.y = f32_to_bf16(v.y);
  o.z = f32_to_bf16(v.z); o.w = f32_to_bf16(v.w);
  ((ushort4*)out)[i] = o;
}

// ---------------- fused big transposes: z=0 Wq (pre-scaled by C2), z=1 Wo ----------------
__global__ __launch_bounds__(256) void wtrans_big(
    const float* __restrict__ wq, unsigned short* __restrict__ dq,
    const float* __restrict__ wo, unsigned short* __restrict__ do_) {
  __shared__ float tile[32][33];
  const float* src = blockIdx.z ? wo : wq;
  unsigned short* dst = blockIdx.z ? do_ : dq;
  const float m = blockIdx.z ? 1.0f : C2;
  int c0 = blockIdx.x * 32, r0 = blockIdx.y * 32;
  int tx = threadIdx.x & 31, ty = threadIdx.x >> 5;
#pragma unroll
  for (int i = 0; i < 32; i += 8)
    tile[ty + i][tx] = src[(size_t)(r0 + ty + i) * 2048 + c0 + tx];
  __syncthreads();
#pragma unroll
  for (int i = 0; i < 32; i += 8)
    dst[(size_t)(c0 + ty + i) * 2048 + r0 + tx] = f32_to_bf16(tile[tx][ty + i] * m);
}

// ---------------- fused small transposes: z=0 Wk (+bias concat), z=1 Wv ----------------
__global__ __launch_bounds__(256) void wtrans_small(
    const float* __restrict__ wk, const float* __restrict__ wv,
    unsigned short* __restrict__ dk, unsigned short* __restrict__ dv,
    const float* __restrict__ bq, const float* __restrict__ bk,
    const float* __restrict__ bv, float* __restrict__ biasout) {
  __shared__ float tile[32][33];
  const float* src = blockIdx.z ? wv : wk;
  unsigned short* dst = blockIdx.z ? dv : dk;
  int c0 = blockIdx.x * 32, r0 = blockIdx.y * 32;
  int tx = threadIdx.x & 31, ty = threadIdx.x >> 5;
#pragma unroll
  for (int i = 0; i < 32; i += 8)
    tile[ty + i][tx] = src[(size_t)(r0 + ty + i) * 128 + c0 + tx];
  __syncthreads();
#pragma unroll
  for (int i = 0; i < 32; i += 8)
    dst[(size_t)(c0 + ty + i) * 2048 + r0 + tx] = f32_to_bf16(tile[tx][ty + i]);
  if (blockIdx.z == 0) {
    int lb = blockIdx.y * 4 + blockIdx.x;
    if (lb < 9) {
      int i = lb * 256 + threadIdx.x;
      if (i < 2304)
        biasout[i] = (i < 2048) ? bq[i] * C2
                                : ((i < 2176) ? bk[i - 2048] : bv[i - 2176]);
    }
  }
}

// ---------------- V transpose per batch (z = batch): [2048][128] -> [128][2048] -------
// Key dim PERMUTED within each 64-tile so attention's PV B-fragments come straight
// from the S^T MFMA output registers (no LDS round-trip for P).
__global__ __launch_bounds__(256) void vtrans(
    const unsigned short* __restrict__ qkv, unsigned short* __restrict__ vt) {
  __shared__ unsigned short tile[32][33];
  const unsigned short* src = qkv + (size_t)blockIdx.z * SEQ * 2304 + 2176;
  unsigned short* dst = vt + (size_t)blockIdx.z * 128 * SEQ;
  int c0 = blockIdx.x * 32, r0 = blockIdx.y * 32;
  int tx = threadIdx.x & 31, ty = threadIdx.x >> 5;
#pragma unroll
  for (int i = 0; i < 32; i += 8)
    tile[ty + i][tx] = src[(size_t)(r0 + ty + i) * 2304 + c0 + tx];
  __syncthreads();
  const int s = r0 + tx;  // key index
  const int col = (s & ~63) | (((s >> 5) & 1) * 32 + ((s >> 2) & 3) * 8 +
                               ((s >> 4) & 1) * 4 + (s & 3));
#pragma unroll
  for (int i = 0; i < 32; i += 8)
    dst[(size_t)(c0 + ty + i) * SEQ + col] = tile[tx][ty + i];
}

// ---------------- gemm_bt: C[M][N] = A[M][K] * BT[N][K]^T + bias ----------------
template <int BN>
__global__ __launch_bounds__(256) void gemm_bt(
    const unsigned short* __restrict__ A,
    const unsigned short* __restrict__ BT,
    const float* __restrict__ bias,
    void* __restrict__ C, int K, int ldc, int outBf16) {
  constexpr int NT = BN / 32;
  __shared__ unsigned short As[128 * 64];
  __shared__ unsigned short Bs[BN * 64];
  const int tid = threadIdx.x;
  const int lane = tid & 63;
  const int wave = tid >> 6;
  const int wr = wave >> 1, wc = wave & 1;
  const int ml = lane & 15, quad = lane >> 4;
  const long bm = (long)blockIdx.x * 128;
  const long bn = (long)blockIdx.y * BN;

  const f32x4 zero4 = {0.f, 0.f, 0.f, 0.f};
  f32x4 acc[4][NT];
#pragma unroll
  for (int mt = 0; mt < 4; ++mt)
#pragma unroll
    for (int nt = 0; nt < NT; ++nt) acc[mt][nt] = zero4;

  const int srow = lane >> 3;
  const int scol = ((lane & 7) ^ srow) * 8;

  for (int k0 = 0; k0 < K; k0 += 64) {
    __syncthreads();
#pragma unroll
    for (int r = 0; r < 4; ++r) {
      const int rowb = r * 32 + wave * 8;
      gload_lds16(A + (bm + rowb + srow) * (long)K + k0 + scol, &As[rowb * 64]);
    }
#pragma unroll
    for (int r = 0; r < NT; ++r) {
      const int rowb = r * 32 + wave * 8;
      gload_lds16(BT + (bn + rowb + srow) * (long)K + k0 + scol, &Bs[rowb * 64]);
    }
    __syncthreads();
#pragma unroll
    for (int kk = 0; kk < 64; kk += 32) {
      const int g0 = (kk >> 3) + quad;
      bf16x8 af[4], bf[NT];
#pragma unroll
      for (int mt = 0; mt < 4; ++mt)
        af[mt] = *(const bf16x8*)&As[(wr * 64 + mt * 16 + ml) * 64 +
                                     ((g0 ^ (ml & 7)) << 3)];
#pragma unroll
      for (int nt = 0; nt < NT; ++nt)
        bf[nt] = *(const bf16x8*)&Bs[(wc * (BN / 2) + nt * 16 + ml) * 64 +
                                     ((g0 ^ (ml & 7)) << 3)];
#pragma unroll
      for (int mt = 0; mt < 4; ++mt)
#pragma unroll
        for (int nt = 0; nt < NT; ++nt)
          acc[mt][nt] = __builtin_amdgcn_mfma_f32_16x16x32_bf16(
              af[mt], bf[nt], acc[mt][nt], 0, 0, 0);
    }
  }

#pragma unroll
  for (int mt = 0; mt < 4; ++mt) {
#pragma unroll
    for (int nt = 0; nt < NT; ++nt) {
      const long col = bn + wc * (BN / 2) + nt * 16 + ml;
      const float bval = bias ? bias[col] : 0.f;
#pragma unroll
      for (int r = 0; r < 4; ++r) {
        const long row = bm + wr * 64 + mt * 16 + quad * 4 + r;
        const float v = acc[mt][nt][r] + bval;
        if (outBf16)
          ((unsigned short*)C)[row * ldc + col] = f32_to_bf16(v);
        else
          ((float*)C)[row * ldc + col] = v;
      }
    }
  }
}

// ---------------- flash MQA attention, v3 ----------------
// grid (SEQ/128, NHEADS, NB) = 512 blocks = 2/CU. 32 qrows/wave.
// S^T = K·Q^T (K from LDS dbuf as A, pre-scaled Q registers as B). P = exp2(S)
// stays in registers (v_perm truncation pack) and feeds PV directly as B-operand
// (V columns pre-permuted by vtrans). V A-frags load DIRECTLY from global/L2 —
// no LDS, issued right after the barrier so latency hides behind the S phase.
// Row-sums l computed by an extra ones-row MFMA (consistent with truncated P).
__global__ __launch_bounds__(256, 2) void mqa_attn(
    const unsigned short* __restrict__ qkv,  // [B*S][2304]: Q | K(2048) | V(2176)
    const unsigned short* __restrict__ vt,   // [B][128][S], key-permuted per 64
    unsigned short* __restrict__ outp) {     // [B*S][2048]
  __shared__ unsigned short Ks[2][64 * 128];   // 2 x 16 KiB, rows swizzled g^(r&15)

  const int lane = threadIdx.x & 63;
  const int wave = threadIdx.x >> 6;
  const int ml = lane & 15, quad = lane >> 4;
  const int h = blockIdx.y, b = blockIdx.z;
  const long q0 = (long)blockIdx.x * 128;
  const long base = (long)b * SEQ;

  // Q fragments (B-operand of S^T); Wq pre-scaled by C2.
  bf16x8 aq[2][4];
#pragma unroll
  for (int n = 0; n < 2; ++n) {
    const unsigned short* qrow =
        qkv + (base + q0 + wave * 32 + n * 16 + ml) * 2304 + h * 128;
#pragma unroll
    for (int ks = 0; ks < 4; ++ks)
      aq[n][ks] = *(const bf16x8*)(qrow + ks * 32 + quad * 8);
  }

  const f32x4 zero4 = {0.f, 0.f, 0.f, 0.f};
  f32x4 o[8][2];
#pragma unroll
  for (int mt2 = 0; mt2 < 8; ++mt2)
#pragma unroll
    for (int n = 0; n < 2; ++n) o[mt2][n] = zero4;
  f32x4 o9[2] = {zero4, zero4};  // ones-row accumulator: row0 = sum_k P = l

  // ones-tile A-frag: row 0 (lane ml==0) = 1.0bf16, other rows 0.
  bf16x8 ones_af;
  {
    union { unsigned u[4]; bf16x8 v; } cv;
    const unsigned w = (ml == 0) ? 0x3F803F80u : 0u;
    cv.u[0] = w; cv.u[1] = w; cv.u[2] = w; cv.u[3] = w;
    ones_af = cv.v;
  }

  // K staging lane decomposition
  const int srowK = lane >> 4;
  const int scolK = ((lane & 15) ^ (wave * 4 + srowK)) * 8;
  const unsigned short* kp = qkv + (base + srowK) * 2304 + 2048 + scolK;

  // V direct-load base pointers: row = mt2*16+ml, byte col offset quad*8 elems.
  const unsigned short* vb[8];
#pragma unroll
  for (int mt2 = 0; mt2 < 8; ++mt2)
    vb[mt2] = vt + ((long)b * 128 + mt2 * 16 + ml) * SEQ + quad * 8;

  auto stageK = [&](int buf, int ktn) {
    const unsigned short* kpp = kp + (long)ktn * (64 * 2304);
#pragma unroll
    for (int r = 0; r < 4; ++r) {
      const int rowb = r * 16 + wave * 4;
      gload_lds16(kpp + (long)rowb * 2304, &Ks[buf][rowb * 128]);
    }
  };

  stageK(0, 0);

  for (int kt = 0; kt < SEQ / 64; ++kt) {
    const int cur = kt & 1;
    __syncthreads();                                  // drains cur K-DMA
    if (kt < SEQ / 64 - 1) stageK(cur ^ 1, kt + 1);   // prefetch overlaps compute

    // issue V loads for this kt now; first use is ~the whole S phase later.
    bf16x8 av[8][2];
#pragma unroll
    for (int mt2 = 0; mt2 < 8; ++mt2)
#pragma unroll
      for (int ks2 = 0; ks2 < 2; ++ks2)
        av[mt2][ks2] = *(const bf16x8*)(vb[mt2] + kt * 64 + ks2 * 32);

    // S^T = K·Q^T : 4 key-mtiles x 2 qrow-ntiles x 4 ksteps (d); pre-scaled.
    f32x4 s[4][2];
#pragma unroll
    for (int mt = 0; mt < 4; ++mt)
#pragma unroll
      for (int n = 0; n < 2; ++n) s[mt][n] = zero4;
#pragma unroll
    for (int ks = 0; ks < 4; ++ks) {
#pragma unroll
      for (int mt = 0; mt < 4; ++mt) {
        bf16x8 ak = *(const bf16x8*)&Ks[cur][(mt * 16 + ml) * 128 +
                                            (((ks * 4 + quad) ^ ml) << 3)];
#pragma unroll
        for (int n = 0; n < 2; ++n)
          s[mt][n] = __builtin_amdgcn_mfma_f32_16x16x32_bf16(
              ak, aq[n][ks], s[mt][n], 0, 0, 0);
      }
    }

    // P = exp2(S) in registers; truncation-pack to bf16 pairs (1 v_perm each).
    unsigned pk[2][4][2];
#pragma unroll
    for (int mt = 0; mt < 4; ++mt)
#pragma unroll
      for (int n = 0; n < 2; ++n) {
        const float p0 = __builtin_amdgcn_exp2f(s[mt][n][0]);
        const float p1 = __builtin_amdgcn_exp2f(s[mt][n][1]);
        const float p2 = __builtin_amdgcn_exp2f(s[mt][n][2]);
        const float p3 = __builtin_amdgcn_exp2f(s[mt][n][3]);
        pk[n][mt][0] = pack_bf16x2_trunc(p0, p1);
        pk[n][mt][1] = pack_bf16x2_trunc(p2, p3);
      }

    // O^T += V^T·P^T, plus ones-row MFMA accumulating l from the SAME bf16 P.
#pragma unroll
    for (int ks2 = 0; ks2 < 2; ++ks2) {
      bf16x8 bp[2];
#pragma unroll
      for (int n = 0; n < 2; ++n) {
        union { unsigned u[4]; bf16x8 v; } cv;
        cv.u[0] = pk[n][2 * ks2][0];
        cv.u[1] = pk[n][2 * ks2][1];
        cv.u[2] = pk[n][2 * ks2 + 1][0];
        cv.u[3] = pk[n][2 * ks2 + 1][1];
        bp[n] = cv.v;
      }
#pragma unroll
      for (int n = 0; n < 2; ++n)
        o9[n] = __builtin_amdgcn_mfma_f32_16x16x32_bf16(
            ones_af, bp[n], o9[n], 0, 0, 0);
#pragma unroll
      for (int mt2 = 0; mt2 < 8; ++mt2) {
#pragma unroll
        for (int n = 0; n < 2; ++n)
          o[mt2][n] = __builtin_amdgcn_mfma_f32_16x16x32_bf16(
              av[mt2][ks2], bp[n], o[mt2][n], 0, 0, 0);
      }
    }
  }

  // l lives at lane (quad=0, ml) reg0 of o9: broadcast across the 16-group.
  float inv[2];
#pragma unroll
  for (int n = 0; n < 2; ++n)
    inv[n] = 1.f / __shfl(o9[n][0], ml);

  // O^T C-layout: lane holds O[qrow=ml][d = mt2*16+quad*4+r] -> 8B packed stores.
#pragma unroll
  for (int n = 0; n < 2; ++n) {
    const long row = base + q0 + wave * 32 + n * 16 + ml;
#pragma unroll
    for (int mt2 = 0; mt2 < 8; ++mt2) {
      uint2 w;
      w.x = pack_bf16x2(o[mt2][n][0] * inv[n], o[mt2][n][1] * inv[n]);
      w.y = pack_bf16x2(o[mt2][n][2] * inv[n], o[mt2][n][3] * inv[n]);
      *(uint2*)&outp[row * HIDN + h * HDIM + mt2 * 16 + quad * 4] = w;
    }
  }
}

extern "C" void kernel_launch(void* const* d_in, const int* in_sizes, int n_in,
                              void* d_out, int out_size, void* d_ws, size_t ws_size,
                              hipStream_t stream) {
  const float* hidden = (const float*)d_in[0];
  const float* Wq = (const float*)d_in[1];
  const float* bq = (const float*)d_in[2];
  const float* Wk = (const float*)d_in[3];
  const float* bk = (const float*)d_in[4];
  const float* Wv = (const float*)d_in[5];
  const float* bv = (const float*)d_in[6];
  const float* Wo = (const float*)d_in[7];
  const float* bo = (const float*)d_in[8];
  float* out = (float*)d_out;

  char* ws = (char*)d_ws;
  const size_t MB = 1u << 20;
  unsigned short* hb    = (unsigned short*)(ws);            // 16 MiB [4096][2048] bf16 hidden
  unsigned short* attn  = hb;                               // aliases hb (dead after QKV gemm)
  unsigned short* wqkvT = (unsigned short*)(ws + 16 * MB);  // 9 MiB  [2304][2048]
  unsigned short* woT   = (unsigned short*)(ws + 25 * MB);  // 8 MiB  [2048][2048]
  unsigned short* qkv   = (unsigned short*)(ws + 33 * MB);  // 18 MiB [4096][2304]
  unsigned short* vt    = (unsigned short*)(ws + 51 * MB);  // 1 MiB  [2][128][2048]
  float* biasqkv        = (float*)(ws + 52 * MB);           // 9 KiB  [2304]

  // 1. prep
  cast_f32_bf16<<<8192, 256, 0, stream>>>(hidden, hb, (NB * SEQ * HIDN) / 4);
  wtrans_big<<<dim3(64, 64, 2), 256, 0, stream>>>(Wq, wqkvT, Wo, woT);
  wtrans_small<<<dim3(4, 64, 2), 256, 0, stream>>>(
      Wk, Wv, wqkvT + (size_t)2048 * 2048, wqkvT + (size_t)2176 * 2048,
      bq, bk, bv, biasqkv);

  // 2. QKV projection (768 blocks = 3/CU exact)
  gemm_bt<96><<<dim3(32, 24), 256, 0, stream>>>(hb, wqkvT, biasqkv, qkv, 2048, 2304, 1);

  // 3. V transpose (key-permuted) per batch
  vtrans<<<dim3(4, 64, 2), 256, 0, stream>>>(qkv, vt);

  // 4. attention (512 blocks = 2/CU exact)
  mqa_attn<<<dim3(SEQ / 128, NHEADS, NB), 256, 0, stream>>>(qkv, vt, attn);

  // 5. output projection (512 = 2/CU exact)
  gemm_bt<128><<<dim3(32, 16), 256, 0, stream>>>(attn, woT, bo, out, 2048, 2048, 0);
}

// Round 7
// 282.601 us; speedup vs baseline: 1.2626x; 1.2626x over previous
//
#include <hip/hip_runtime.h>
#include <math.h>

#define HIDN 2048
#define NHEADS 16
#define HDIM 128
#define SEQ 2048
#define NB 2

// scale * log2(e), folded into Wq/bq so S arrives pre-scaled for exp2.
#define C2 0.12751744154f

typedef __bf16 bf16x8 __attribute__((ext_vector_type(8)));
typedef float f32x4 __attribute__((ext_vector_type(4)));

__device__ __forceinline__ unsigned short f32_to_bf16(float f) {
  unsigned int u = __float_as_uint(f);
  u += 0x7FFFu + ((u >> 16) & 1u);   // round-to-nearest-even
  return (unsigned short)(u >> 16);
}

__device__ __forceinline__ unsigned pack_bf16x2(float a, float b) {
  return (unsigned)f32_to_bf16(a) | ((unsigned)f32_to_bf16(b) << 16);
}

// pack two f32 to bf16x2 by TRUNCATION in one v_perm_b32.
__device__ __forceinline__ unsigned pack_bf16x2_trunc(float a, float b) {
  return __builtin_amdgcn_perm(__float_as_uint(b), __float_as_uint(a), 0x07060302u);
}

// async global->LDS, 16B/lane. LDS dest is wave-uniform base + lane*16 (m104/m108).
__device__ __forceinline__ void gload_lds16(const void* g, void* l) {
  __builtin_amdgcn_global_load_lds(
      (__attribute__((address_space(1))) void*)(g),
      (__attribute__((address_space(3))) void*)(l), 16, 0, 0);
}

// ---------------- elementwise cast fp32 -> bf16 ----------------
__global__ __launch_bounds__(256) void cast_f32_bf16(
    const float* __restrict__ in, unsigned short* __restrict__ out, int n4) {
  int i = blockIdx.x * blockDim.x + threadIdx.x;
  if (i >= n4) return;
  float4 v = ((const float4*)in)[i];
  ushort4 o;
  o.x = f32_to_bf16(v.x); o.y = f32_to_bf16(v.y);
  o.z = f32_to_bf16(v.z); o.w = f32_to_bf16(v.w);
  ((ushort4*)out)[i] = o;
}

// ---------------- fused big transposes: z=0 Wq (pre-scaled by C2), z=1 Wo ----------------
__global__ __launch_bounds__(256) void wtrans_big(
    const float* __restrict__ wq, unsigned short* __restrict__ dq,
    const float* __restrict__ wo, unsigned short* __restrict__ do_) {
  __shared__ float tile[32][33];
  const float* src = blockIdx.z ? wo : wq;
  unsigned short* dst = blockIdx.z ? do_ : dq;
  const float m = blockIdx.z ? 1.0f : C2;
  int c0 = blockIdx.x * 32, r0 = blockIdx.y * 32;
  int tx = threadIdx.x & 31, ty = threadIdx.x >> 5;
#pragma unroll
  for (int i = 0; i < 32; i += 8)
    tile[ty + i][tx] = src[(size_t)(r0 + ty + i) * 2048 + c0 + tx];
  __syncthreads();
#pragma unroll
  for (int i = 0; i < 32; i += 8)
    dst[(size_t)(c0 + ty + i) * 2048 + r0 + tx] = f32_to_bf16(tile[tx][ty + i] * m);
}

// ---------------- fused small transposes: z=0 Wk (+bias concat), z=1 Wv ----------------
__global__ __launch_bounds__(256) void wtrans_small(
    const float* __restrict__ wk, const float* __restrict__ wv,
    unsigned short* __restrict__ dk, unsigned short* __restrict__ dv,
    const float* __restrict__ bq, const float* __restrict__ bk,
    const float* __restrict__ bv, float* __restrict__ biasout) {
  __shared__ float tile[32][33];
  const float* src = blockIdx.z ? wv : wk;
  unsigned short* dst = blockIdx.z ? dv : dk;
  int c0 = blockIdx.x * 32, r0 = blockIdx.y * 32;
  int tx = threadIdx.x & 31, ty = threadIdx.x >> 5;
#pragma unroll
  for (int i = 0; i < 32; i += 8)
    tile[ty + i][tx] = src[(size_t)(r0 + ty + i) * 128 + c0 + tx];
  __syncthreads();
#pragma unroll
  for (int i = 0; i < 32; i += 8)
    dst[(size_t)(c0 + ty + i) * 2048 + r0 + tx] = f32_to_bf16(tile[tx][ty + i]);
  if (blockIdx.z == 0) {
    int lb = blockIdx.y * 4 + blockIdx.x;
    if (lb < 9) {
      int i = lb * 256 + threadIdx.x;
      if (i < 2304)
        biasout[i] = (i < 2048) ? bq[i] * C2
                                : ((i < 2176) ? bk[i - 2048] : bv[i - 2176]);
    }
  }
}

// ---------------- V transpose per batch (z = batch): [2048][128] -> [128][2048] -------
// Key dim PERMUTED within each 64-tile so attention's PV B-fragments come straight
// from the S^T MFMA output registers (no LDS round-trip for P).
__global__ __launch_bounds__(256) void vtrans(
    const unsigned short* __restrict__ qkv, unsigned short* __restrict__ vt) {
  __shared__ unsigned short tile[32][33];
  const unsigned short* src = qkv + (size_t)blockIdx.z * SEQ * 2304 + 2176;
  unsigned short* dst = vt + (size_t)blockIdx.z * 128 * SEQ;
  int c0 = blockIdx.x * 32, r0 = blockIdx.y * 32;
  int tx = threadIdx.x & 31, ty = threadIdx.x >> 5;
#pragma unroll
  for (int i = 0; i < 32; i += 8)
    tile[ty + i][tx] = src[(size_t)(r0 + ty + i) * 2304 + c0 + tx];
  __syncthreads();
  const int s = r0 + tx;  // key index
  const int col = (s & ~63) | (((s >> 5) & 1) * 32 + ((s >> 2) & 3) * 8 +
                               ((s >> 4) & 1) * 4 + (s & 3));
#pragma unroll
  for (int i = 0; i < 32; i += 8)
    dst[(size_t)(c0 + ty + i) * SEQ + col] = tile[tx][ty + i];
}

// ---------------- gemm_bt: C[M][N] = A[M][K] * BT[N][K]^T + bias ----------------
template <int BN>
__global__ __launch_bounds__(256) void gemm_bt(
    const unsigned short* __restrict__ A,
    const unsigned short* __restrict__ BT,
    const float* __restrict__ bias,
    void* __restrict__ C, int K, int ldc, int outBf16) {
  constexpr int NT = BN / 32;
  __shared__ unsigned short As[128 * 64];
  __shared__ unsigned short Bs[BN * 64];
  const int tid = threadIdx.x;
  const int lane = tid & 63;
  const int wave = tid >> 6;
  const int wr = wave >> 1, wc = wave & 1;
  const int ml = lane & 15, quad = lane >> 4;
  const long bm = (long)blockIdx.x * 128;
  const long bn = (long)blockIdx.y * BN;

  const f32x4 zero4 = {0.f, 0.f, 0.f, 0.f};
  f32x4 acc[4][NT];
#pragma unroll
  for (int mt = 0; mt < 4; ++mt)
#pragma unroll
    for (int nt = 0; nt < NT; ++nt) acc[mt][nt] = zero4;

  const int srow = lane >> 3;
  const int scol = ((lane & 7) ^ srow) * 8;

  for (int k0 = 0; k0 < K; k0 += 64) {
    __syncthreads();
#pragma unroll
    for (int r = 0; r < 4; ++r) {
      const int rowb = r * 32 + wave * 8;
      gload_lds16(A + (bm + rowb + srow) * (long)K + k0 + scol, &As[rowb * 64]);
    }
#pragma unroll
    for (int r = 0; r < NT; ++r) {
      const int rowb = r * 32 + wave * 8;
      gload_lds16(BT + (bn + rowb + srow) * (long)K + k0 + scol, &Bs[rowb * 64]);
    }
    __syncthreads();
#pragma unroll
    for (int kk = 0; kk < 64; kk += 32) {
      const int g0 = (kk >> 3) + quad;
      bf16x8 af[4], bf[NT];
#pragma unroll
      for (int mt = 0; mt < 4; ++mt)
        af[mt] = *(const bf16x8*)&As[(wr * 64 + mt * 16 + ml) * 64 +
                                     ((g0 ^ (ml & 7)) << 3)];
#pragma unroll
      for (int nt = 0; nt < NT; ++nt)
        bf[nt] = *(const bf16x8*)&Bs[(wc * (BN / 2) + nt * 16 + ml) * 64 +
                                     ((g0 ^ (ml & 7)) << 3)];
#pragma unroll
      for (int mt = 0; mt < 4; ++mt)
#pragma unroll
        for (int nt = 0; nt < NT; ++nt)
          acc[mt][nt] = __builtin_amdgcn_mfma_f32_16x16x32_bf16(
              af[mt], bf[nt], acc[mt][nt], 0, 0, 0);
    }
  }

#pragma unroll
  for (int mt = 0; mt < 4; ++mt) {
#pragma unroll
    for (int nt = 0; nt < NT; ++nt) {
      const long col = bn + wc * (BN / 2) + nt * 16 + ml;
      const float bval = bias ? bias[col] : 0.f;
#pragma unroll
      for (int r = 0; r < 4; ++r) {
        const long row = bm + wr * 64 + mt * 16 + quad * 4 + r;
        const float v = acc[mt][nt][r] + bval;
        if (outBf16)
          ((unsigned short*)C)[row * ldc + col] = f32_to_bf16(v);
        else
          ((float*)C)[row * ldc + col] = v;
      }
    }
  }
}

// ---------------- flash MQA attention, v4 = R5 structure + R6 VALU cuts -------
// grid (SEQ/128, NHEADS, NB) = 512 blocks = 2/CU. 32 qrows/wave.
// S^T = K·Q^T (K from LDS dbuf as A, pre-scaled Q registers as B). P = exp2(S)
// stays in registers (v_perm truncation pack) and feeds PV directly as B-operand
// (V columns pre-permuted by vtrans). V staged via LDS-DMA dbuf (NOT direct
// loads — R6 showed the 16-row gather through VMEM is latency-death; the DMA
// engine does the scatter for free). Row-sums via ones-row MFMA. 1 barrier/kt.
__global__ __launch_bounds__(256, 2) void mqa_attn(
    const unsigned short* __restrict__ qkv,  // [B*S][2304]: Q | K(2048) | V(2176)
    const unsigned short* __restrict__ vt,   // [B][128][S], key-permuted per 64
    unsigned short* __restrict__ outp) {     // [B*S][2048]
  __shared__ unsigned short Ks[2][64 * 128];   // 2 x 16 KiB, rows swizzled g^(r&15)
  __shared__ unsigned short VTs[2][128 * 64];  // 2 x 16 KiB, rows swizzled g^(r&7)

  const int lane = threadIdx.x & 63;
  const int wave = threadIdx.x >> 6;
  const int ml = lane & 15, quad = lane >> 4;
  const int h = blockIdx.y, b = blockIdx.z;
  const long q0 = (long)blockIdx.x * 128;
  const long base = (long)b * SEQ;

  // Q fragments (B-operand of S^T); Wq pre-scaled by C2.
  bf16x8 aq[2][4];
#pragma unroll
  for (int n = 0; n < 2; ++n) {
    const unsigned short* qrow =
        qkv + (base + q0 + wave * 32 + n * 16 + ml) * 2304 + h * 128;
#pragma unroll
    for (int ks = 0; ks < 4; ++ks)
      aq[n][ks] = *(const bf16x8*)(qrow + ks * 32 + quad * 8);
  }

  const f32x4 zero4 = {0.f, 0.f, 0.f, 0.f};
  f32x4 o[8][2];
#pragma unroll
  for (int mt2 = 0; mt2 < 8; ++mt2)
#pragma unroll
    for (int n = 0; n < 2; ++n) o[mt2][n] = zero4;
  f32x4 o9[2] = {zero4, zero4};  // ones-row accumulator: row0 = sum_k P = l

  // ones-tile A-frag: row 0 (lane ml==0) = 1.0bf16, other rows 0.
  bf16x8 ones_af;
  {
    union { unsigned u[4]; bf16x8 v; } cv;
    const unsigned w = (ml == 0) ? 0x3F803F80u : 0u;
    cv.u[0] = w; cv.u[1] = w; cv.u[2] = w; cv.u[3] = w;
    ones_af = cv.v;
  }

  // staging lane decomposition
  const int srowK = lane >> 4;
  const int scolK = ((lane & 15) ^ (wave * 4 + srowK)) * 8;
  const int srowV = lane >> 3;
  const int scolV = ((lane & 7) ^ srowV) * 8;
  const unsigned short* kp = qkv + (base + srowK) * 2304 + 2048 + scolK;
  const unsigned short* vp = vt + ((long)b * 128 + srowV) * SEQ + scolV;

  auto stage = [&](int buf, int ktn) {
    const unsigned short* kpp = kp + (long)ktn * (64 * 2304);
    const unsigned short* vpp = vp + ktn * 64;
#pragma unroll
    for (int r = 0; r < 4; ++r) {
      const int rowb = r * 16 + wave * 4;
      gload_lds16(kpp + (long)rowb * 2304, &Ks[buf][rowb * 128]);
    }
#pragma unroll
    for (int r = 0; r < 4; ++r) {
      const int rowb = r * 32 + wave * 8;
      gload_lds16(vpp + (long)rowb * SEQ, &VTs[buf][rowb * 64]);
    }
  };

  stage(0, 0);

  for (int kt = 0; kt < SEQ / 64; ++kt) {
    const int cur = kt & 1;
    __syncthreads();                                // drains cur-buffer DMA
    if (kt < SEQ / 64 - 1) stage(cur ^ 1, kt + 1);  // prefetch overlaps compute

    // S^T = K·Q^T : 4 key-mtiles x 2 qrow-ntiles x 4 ksteps (d); pre-scaled.
    f32x4 s[4][2];
#pragma unroll
    for (int mt = 0; mt < 4; ++mt)
#pragma unroll
      for (int n = 0; n < 2; ++n) s[mt][n] = zero4;
#pragma unroll
    for (int ks = 0; ks < 4; ++ks) {
#pragma unroll
      for (int mt = 0; mt < 4; ++mt) {
        bf16x8 ak = *(const bf16x8*)&Ks[cur][(mt * 16 + ml) * 128 +
                                            (((ks * 4 + quad) ^ ml) << 3)];
#pragma unroll
        for (int n = 0; n < 2; ++n)
          s[mt][n] = __builtin_amdgcn_mfma_f32_16x16x32_bf16(
              ak, aq[n][ks], s[mt][n], 0, 0, 0);
      }
    }

    // P = exp2(S) in registers; truncation-pack to bf16 pairs (1 v_perm each).
    unsigned pk[2][4][2];
#pragma unroll
    for (int mt = 0; mt < 4; ++mt)
#pragma unroll
      for (int n = 0; n < 2; ++n) {
        const float p0 = __builtin_amdgcn_exp2f(s[mt][n][0]);
        const float p1 = __builtin_amdgcn_exp2f(s[mt][n][1]);
        const float p2 = __builtin_amdgcn_exp2f(s[mt][n][2]);
        const float p3 = __builtin_amdgcn_exp2f(s[mt][n][3]);
        pk[n][mt][0] = pack_bf16x2_trunc(p0, p1);
        pk[n][mt][1] = pack_bf16x2_trunc(p2, p3);
      }

    // O^T += V^T·P^T, plus ones-row MFMA accumulating l from the SAME bf16 P.
#pragma unroll
    for (int ks2 = 0; ks2 < 2; ++ks2) {
      bf16x8 bp[2];
#pragma unroll
      for (int n = 0; n < 2; ++n) {
        union { unsigned u[4]; bf16x8 v; } cv;
        cv.u[0] = pk[n][2 * ks2][0];
        cv.u[1] = pk[n][2 * ks2][1];
        cv.u[2] = pk[n][2 * ks2 + 1][0];
        cv.u[3] = pk[n][2 * ks2 + 1][1];
        bp[n] = cv.v;
      }
#pragma unroll
      for (int n = 0; n < 2; ++n)
        o9[n] = __builtin_amdgcn_mfma_f32_16x16x32_bf16(
            ones_af, bp[n], o9[n], 0, 0, 0);
#pragma unroll
      for (int mt2 = 0; mt2 < 8; ++mt2) {
        bf16x8 av = *(const bf16x8*)&VTs[cur][(mt2 * 16 + ml) * 64 +
                                             (((ks2 * 4 + quad) ^ (ml & 7)) << 3)];
#pragma unroll
        for (int n = 0; n < 2; ++n)
          o[mt2][n] = __builtin_amdgcn_mfma_f32_16x16x32_bf16(
              av, bp[n], o[mt2][n], 0, 0, 0);
      }
    }
  }

  // l lives at lane (quad=0, ml) reg0 of o9: broadcast across the 16-group.
  float inv[2];
#pragma unroll
  for (int n = 0; n < 2; ++n)
    inv[n] = 1.f / __shfl(o9[n][0], ml);

  // O^T C-layout: lane holds O[qrow=ml][d = mt2*16+quad*4+r] -> 8B packed stores.
#pragma unroll
  for (int n = 0; n < 2; ++n) {
    const long row = base + q0 + wave * 32 + n * 16 + ml;
#pragma unroll
    for (int mt2 = 0; mt2 < 8; ++mt2) {
      uint2 w;
      w.x = pack_bf16x2(o[mt2][n][0] * inv[n], o[mt2][n][1] * inv[n]);
      w.y = pack_bf16x2(o[mt2][n][2] * inv[n], o[mt2][n][3] * inv[n]);
      *(uint2*)&outp[row * HIDN + h * HDIM + mt2 * 16 + quad * 4] = w;
    }
  }
}

extern "C" void kernel_launch(void* const* d_in, const int* in_sizes, int n_in,
                              void* d_out, int out_size, void* d_ws, size_t ws_size,
                              hipStream_t stream) {
  const float* hidden = (const float*)d_in[0];
  const float* Wq = (const float*)d_in[1];
  const float* bq = (const float*)d_in[2];
  const float* Wk = (const float*)d_in[3];
  const float* bk = (const float*)d_in[4];
  const float* Wv = (const float*)d_in[5];
  const float* bv = (const float*)d_in[6];
  const float* Wo = (const float*)d_in[7];
  const float* bo = (const float*)d_in[8];
  float* out = (float*)d_out;

  char* ws = (char*)d_ws;
  const size_t MB = 1u << 20;
  unsigned short* hb    = (unsigned short*)(ws);            // 16 MiB [4096][2048] bf16 hidden
  unsigned short* attn  = hb;                               // aliases hb (dead after QKV gemm)
  unsigned short* wqkvT = (unsigned short*)(ws + 16 * MB);  // 9 MiB  [2304][2048]
  unsigned short* woT   = (unsigned short*)(ws + 25 * MB);  // 8 MiB  [2048][2048]
  unsigned short* qkv   = (unsigned short*)(ws + 33 * MB);  // 18 MiB [4096][2304]
  unsigned short* vt    = (unsigned short*)(ws + 51 * MB);  // 1 MiB  [2][128][2048]
  float* biasqkv        = (float*)(ws + 52 * MB);           // 9 KiB  [2304]

  // 1. prep
  cast_f32_bf16<<<8192, 256, 0, stream>>>(hidden, hb, (NB * SEQ * HIDN) / 4);
  wtrans_big<<<dim3(64, 64, 2), 256, 0, stream>>>(Wq, wqkvT, Wo, woT);
  wtrans_small<<<dim3(4, 64, 2), 256, 0, stream>>>(
      Wk, Wv, wqkvT + (size_t)2048 * 2048, wqkvT + (size_t)2176 * 2048,
      bq, bk, bv, biasqkv);

  // 2. QKV projection (768 blocks = 3/CU exact)
  gemm_bt<96><<<dim3(32, 24), 256, 0, stream>>>(hb, wqkvT, biasqkv, qkv, 2048, 2304, 1);

  // 3. V transpose (key-permuted) per batch
  vtrans<<<dim3(4, 64, 2), 256, 0, stream>>>(qkv, vt);

  // 4. attention (512 blocks = 2/CU exact)
  mqa_attn<<<dim3(SEQ / 128, NHEADS, NB), 256, 0, stream>>>(qkv, vt, attn);

  // 5. output projection (512 = 2/CU exact)
  gemm_bt<128><<<dim3(32, 16), 256, 0, stream>>>(attn, woT, bo, out, 2048, 2048, 0);
}